// Round 7
// baseline (81.125 us; speedup 1.0000x reference)
//
#include <hip/hip_runtime.h>

// Laplace attention: N=2, C=512, S=256, fp32.
// weights[n,c,d] = softmax_d( -sum_s |k[n,d,s]-q[n,c,s]| / 2 )
// out[n,c,s] = sum_d weights[n,c,d] * v[n,d,s]
//
// Round-11: kill the k-scatter with rotated-LDS double-buffered staging.
// Round-10 post-mortem: main ~34us vs VALU floor 5.8us / L2-BW floor 7.4us.
// The per-thread-row k stream is a SCATTER: each wave load touches 64
// distinct 64B lines (lanes stride 1KB) -> MSHR-limited to ~2 wave-loads in
// flight -> ~30-40 B/cyc/CU effective -> ~25-30us stall. Fix:
//  - k staged through LDS in 8 chunks of 32 floats/row (64KB), DOUBLE-
//    buffered (2x64KB): chunk ch+1's 8 coalesced wave-loads (16 lines each,
//    dependence-free burst) issue at the top of compute(ch); ds_write after
//    compute; ONE barrier per chunk.
//  - QUAD-ROTATION swizzle p=(q+row)&7 within each 8-quad chunk row:
//    per-thread-row ds_read_b128 AND staging ds_write_b128 are both exactly
//    2-way per 16-lane phase (2-way is free on CDNA4) -- this is what
//    round-8's unrotated [512][36] layout got wrong (8-way, 1.06e7 cycles).
//  - q via LDS uniform-broadcast (conflict-free by definition); v PV reads
//    stay coalesced-global; po partial buffer aliases ksm buf0 (k dead).
//  - Same thread<->d bijection, single-shot softmax, n=b&1 XCD mapping.
// LDS 140.3 KB, 1 block/CU, 13 barriers total.
// Ambient: harness's 256MiB workspace poison fill (~41us at 80% HBM peak)
// is in the timed window and untouchable (workspace unused by us).

constexpr int N_  = 2;
constexpr int C_  = 512;
constexpr int S_  = 256;
constexpr int TC  = 4;             // q rows per block
constexpr int NT  = 512;           // threads per block (thread<->d bijection)
constexpr int NW  = NT / 64;       // 8 waves
constexpr int SC  = 32;            // floats per chunk per k-row
constexpr int SCQ = SC / 4;        // 8 quads per chunk row
constexpr int NCH = S_ / SC;       // 8 chunks
constexpr int KF  = C_ * SCQ / NT; // 8 float4 per thread per chunk stage

// ---- DPP wave-reduce helpers ----
template <int CTRL, int ROW_MASK>
__device__ __forceinline__ float dpp_add(float x) {
    int yi = __builtin_amdgcn_update_dpp(0, __float_as_int(x), CTRL, ROW_MASK, 0xf, true);
    return x + __int_as_float(yi);
}
template <int CTRL, int ROW_MASK>
__device__ __forceinline__ float dpp_max(float x) {
    int yi = __builtin_amdgcn_update_dpp(__float_as_int(x), __float_as_int(x), CTRL, ROW_MASK, 0xf, false);
    return fmaxf(x, __int_as_float(yi));
}
__device__ __forceinline__ float wave_sum_bcast(float x) {
    x = dpp_add<0x111, 0xf>(x);   // row_shr:1
    x = dpp_add<0x112, 0xf>(x);   // row_shr:2
    x = dpp_add<0x114, 0xf>(x);   // row_shr:4
    x = dpp_add<0x118, 0xf>(x);   // row_shr:8
    x = dpp_add<0x142, 0xa>(x);   // row_bcast15
    x = dpp_add<0x143, 0xc>(x);   // row_bcast31 -> lane63 = total
    return __int_as_float(__builtin_amdgcn_readlane(__float_as_int(x), 63));
}
__device__ __forceinline__ float wave_max_bcast(float x) {
    x = dpp_max<0x111, 0xf>(x);
    x = dpp_max<0x112, 0xf>(x);
    x = dpp_max<0x114, 0xf>(x);
    x = dpp_max<0x118, 0xf>(x);
    x = dpp_max<0x142, 0xa>(x);
    x = dpp_max<0x143, 0xc>(x);
    return __int_as_float(__builtin_amdgcn_readlane(__float_as_int(x), 63));
}
__device__ __forceinline__ void fma4(float4& a, const float s, const float4& v) {
    a.x += s * v.x; a.y += s * v.y; a.z += s * v.z; a.w += s * v.w;
}

__global__ __launch_bounds__(NT, 1)
void laplace_attn_fused(const float* __restrict__ qg,
                        const float* __restrict__ kg,
                        const float* __restrict__ vg,
                        float* __restrict__ out) {
    // LDS: ksm 128KB (2 x 64KB chunk buffers, quad-rotated rows)
    //      + qs 4KB + wt 8KB + red 256B = 140.3 KB -> 1 block/CU.
    __shared__ __align__(16) float ksm[2][C_][SC];
    __shared__ __align__(16) float qs[TC][S_];
    __shared__ __align__(16) float wt[C_][TC];
    __shared__ float4 red1[NW];
    __shared__ float4 red2[NW];
    // PV partial buffer aliases ksm[0] (k fully consumed before PV): 32KB<=64KB.
    float4 (*po)[TC][S_ / 4] = (float4 (*)[TC][S_ / 4])&ksm[0][0][0];

    const int b    = blockIdx.x;
    const int n    = b & 1;               // XCD x sees only n = x&1
    const int c0   = (b >> 1) * TC;
    const int tid  = threadIdx.x;
    const int w    = tid >> 6;
    const int lane = tid & 63;

    const float* kn = kg + (size_t)n * C_ * S_;
    const float* vn = vg + (size_t)n * C_ * S_;
    const float* qn = qg + ((size_t)n * C_ + c0) * S_;

    // ---- stage q (4 rows = 256 float4), lane-contiguous ----
    if (tid < TC * (S_ / 4)) {
        const int row = tid >> 6;
        const int col = (tid & 63) << 2;
        *(float4*)&qs[row][col] = *(const float4*)(qn + (size_t)row * S_ + col);
    }

    // staging geometry: thread covers float4 slot f = tid + NT*it of the
    // chunk slab; row(it) = srow + 64*it, source quad sqo, rotated pos sp.
    const int srow = tid >> 3;           // 8 quads per chunk row
    const int sqo  = tid & 7;
    const int sp   = (sqo + srow) & 7;   // (64*it) % 8 == 0 -> it-invariant

    // ---- prologue: stage k chunk 0 into buf 0 ----
    float4 greg[KF];
    #pragma unroll
    for (int it = 0; it < KF; ++it) {
        const int row = srow + (it << 6);
        greg[it] = *(const float4*)(kn + (size_t)row * S_ + (sqo << 2));
    }
    #pragma unroll
    for (int it = 0; it < KF; ++it) {
        const int row = srow + (it << 6);
        *(float4*)&ksm[0][row][sp << 2] = greg[it];
    }
    __syncthreads();

    // ---- logits: thread owns d = tid; double-buffered chunks ----
    float dist0 = 0.f, dist1 = 0.f, dist2 = 0.f, dist3 = 0.f;
    int cur = 0;

    for (int ch = 0; ch < NCH; ++ch) {
        // burst-issue chunk ch+1 loads (coalesced, dependence-free)
        if (ch + 1 < NCH) {
            const float* kc = kn + (ch + 1) * SC;
            #pragma unroll
            for (int it = 0; it < KF; ++it) {
                const int row = srow + (it << 6);
                greg[it] = *(const float4*)(kc + (size_t)row * S_ + (sqo << 2));
            }
        }
        // compute on chunk ch from buf[cur]; k row = tid, rotated quads
        const int sb = ch * SC;
        #pragma unroll
        for (int j = 0; j < SCQ; ++j) {
            const int p = (j + tid) & 7;
            const float4 kf = *(const float4*)&ksm[cur][tid][p << 2];
            const int s = sb + (j << 2);
            const float4 qa = *(const float4*)&qs[0][s];
            const float4 qb = *(const float4*)&qs[1][s];
            const float4 qc = *(const float4*)&qs[2][s];
            const float4 qd = *(const float4*)&qs[3][s];
            dist0 += (fabsf(kf.x - qa.x) + fabsf(kf.y - qa.y))
                   + (fabsf(kf.z - qa.z) + fabsf(kf.w - qa.w));
            dist1 += (fabsf(kf.x - qb.x) + fabsf(kf.y - qb.y))
                   + (fabsf(kf.z - qb.z) + fabsf(kf.w - qb.w));
            dist2 += (fabsf(kf.x - qc.x) + fabsf(kf.y - qc.y))
                   + (fabsf(kf.z - qc.z) + fabsf(kf.w - qc.w));
            dist3 += (fabsf(kf.x - qd.x) + fabsf(kf.y - qd.y))
                   + (fabsf(kf.z - qd.z) + fabsf(kf.w - qd.w));
        }
        // write chunk ch+1 into the other buffer (its readers finished
        // before the barrier that opened chunk ch)
        if (ch + 1 < NCH) {
            #pragma unroll
            for (int it = 0; it < KF; ++it) {
                const int row = srow + (it << 6);
                *(float4*)&ksm[cur ^ 1][row][sp << 2] = greg[it];
            }
            cur ^= 1;
        }
        __syncthreads();
    }

    // ---- block softmax over d (single-shot, 4 components = 4 q-rows) ----
    float4 x;
    x.x = -0.5f * dist0; x.y = -0.5f * dist1;
    x.z = -0.5f * dist2; x.w = -0.5f * dist3;

    float4 mx;
    mx.x = wave_max_bcast(x.x); mx.y = wave_max_bcast(x.y);
    mx.z = wave_max_bcast(x.z); mx.w = wave_max_bcast(x.w);
    if (lane == 0) red1[w] = mx;
    __syncthreads();
    float4 M = red1[0];
    #pragma unroll
    for (int u = 1; u < NW; ++u) {
        const float4 r = red1[u];
        M.x = fmaxf(M.x, r.x); M.y = fmaxf(M.y, r.y);
        M.z = fmaxf(M.z, r.z); M.w = fmaxf(M.w, r.w);
    }

    float4 p;
    p.x = __expf(x.x - M.x); p.y = __expf(x.y - M.y);
    p.z = __expf(x.z - M.z); p.w = __expf(x.w - M.w);

    float4 sv;
    sv.x = wave_sum_bcast(p.x); sv.y = wave_sum_bcast(p.y);
    sv.z = wave_sum_bcast(p.z); sv.w = wave_sum_bcast(p.w);
    if (lane == 0) red2[w] = sv;
    __syncthreads();
    float4 L = red2[0];
    #pragma unroll
    for (int u = 1; u < NW; ++u) {
        const float4 r = red2[u];
        L.x += r.x; L.y += r.y; L.z += r.z; L.w += r.w;
    }
    // pre-normalize weights: PV output needs no epilogue scale
    p.x *= (1.f / L.x); p.y *= (1.f / L.y);
    p.z *= (1.f / L.z); p.w *= (1.f / L.w);
    *(float4*)&wt[tid][0] = p;            // contiguous 16B/thread
    __syncthreads();

    // ---- PV: wave w owns d in [64w, 64w+64); v from global (coalesced) ----
    float4 o0 = make_float4(0.f, 0.f, 0.f, 0.f), o1 = o0, o2 = o0, o3 = o0;
    const int dbase = w << 6;
    #pragma unroll 8
    for (int dd = 0; dd < 64; ++dd) {
        const int d = dbase + dd;
        const float4 vv = *(const float4*)(vn + (size_t)d * S_ + (lane << 2));
        const float4 pw = *(const float4*)&wt[d][0];   // uniform broadcast
        fma4(o0, pw.x, vv); fma4(o1, pw.y, vv);
        fma4(o2, pw.z, vv); fma4(o3, pw.w, vv);
    }
    po[w][0][lane] = o0; po[w][1][lane] = o1;
    po[w][2][lane] = o2; po[w][3][lane] = o3;
    __syncthreads();

    // ---- combine 8 wave-partials, write out ----
    if (tid < TC * 64) {
        const int c    = tid >> 6;
        const int quad = tid & 63;
        float4 s = po[0][c][quad];
        #pragma unroll
        for (int u = 1; u < NW; ++u) {
            const float4 r = po[u][c][quad];
            s.x += r.x; s.y += r.y; s.z += r.z; s.w += r.w;
        }
        *(float4*)(out + ((size_t)n * C_ + c0 + c) * S_ + (quad << 2)) = s;
    }
}

extern "C" void kernel_launch(void* const* d_in, const int* in_sizes, int n_in,
                              void* d_out, int out_size, void* d_ws, size_t ws_size,
                              hipStream_t stream) {
    const float* q = (const float*)d_in[0];
    const float* k = (const float*)d_in[1];
    const float* v = (const float*)d_in[2];
    float* out = (float*)d_out;
    (void)d_ws; (void)ws_size;   // workspace unused

    laplace_attn_fused<<<dim3(N_ * (C_ / TC)), dim3(NT), 0, stream>>>(q, k, v, out);
}

// Round 8
// 81.051 us; speedup vs baseline: 1.0009x; 1.0009x over previous
//
#include <hip/hip_runtime.h>

// Laplace attention: N=2, C=512, S=256, fp32.
// weights[n,c,d] = softmax_d( -sum_s |k[n,d,s]-q[n,c,s]| / 2 )
// out[n,c,s] = sum_d weights[n,c,d] * v[n,d,s]
//
// Round-12: occupancy doubling at constant L2 traffic.
// Rounds 9/10/11 post-mortem: three radically different k-access designs
// (global scatter / line-grouped / coalesced rotated-LDS dbuf) ALL land at
// main ~35us -> access pattern was never the bottleneck. Empirical scaling
// law across rounds: 4 waves/CU=116us, 8 waves/CU=62us, 8 waves tuned=35us,
// VALUBusy ~15% throughout => ~84% latency-stall at 2 waves/SIMD. The
// binding constraint is TLP, and adding BLOCKS is wrong (every block reads
// all k+v => traffic = nblocks x 1MB; L2-BW wall). So:
//  - 1024 threads/block, 256 blocks: 16 waves/CU = 4 waves/SIMD (2x TLP),
//    L2 traffic unchanged (256 MB).
//  - Split-s logits: thread owns d = tid&511, s-half h = tid>>9 (128 elems
//    x 4 c each); halves summed via dpart[2][512][4] in LDS (1 barrier).
//  - Softmax on the lower 8 waves (block-uniform barriers kept outside the
//    divergent region); weights pre-normalized into wt[512][4].
//  - PV: 16 waves x 32 d-rows each; po[16][4][64] float4 combine.
//  - All LDS patterns lane-contiguous or uniform-broadcast (the two
//    measured-conflict-free classes). k streamed per-thread from global
//    (pattern proven non-binding in R5-R7).
//  - __launch_bounds__(1024,4): VGPR cap 128 so all 16 waves co-reside.
//  - LDS 92.3 KB -> 1 block/CU; 7 barriers total; n=b&1 XCD mapping.
// Ambient: harness's 256MiB workspace poison fill (~41us, 80% HBM peak)
// sits in the timed window; workspace unused by us.

constexpr int N_  = 2;
constexpr int C_  = 512;
constexpr int S_  = 256;
constexpr int TC  = 4;             // q rows per block
constexpr int NT  = 1024;          // threads per block (16 waves)
constexpr int NWA = NT / 64;       // 16 waves
constexpr int NWH = C_ / 64;       // 8 waves cover d in softmax
constexpr int SH  = S_ / 2;        // s-half per thread (128)
constexpr int DPW = C_ / NWA;      // 32 d-rows per wave in PV

// ---- DPP wave-reduce helpers ----
template <int CTRL, int ROW_MASK>
__device__ __forceinline__ float dpp_add(float x) {
    int yi = __builtin_amdgcn_update_dpp(0, __float_as_int(x), CTRL, ROW_MASK, 0xf, true);
    return x + __int_as_float(yi);
}
template <int CTRL, int ROW_MASK>
__device__ __forceinline__ float dpp_max(float x) {
    int yi = __builtin_amdgcn_update_dpp(__float_as_int(x), __float_as_int(x), CTRL, ROW_MASK, 0xf, false);
    return fmaxf(x, __int_as_float(yi));
}
__device__ __forceinline__ float wave_sum_bcast(float x) {
    x = dpp_add<0x111, 0xf>(x);   // row_shr:1
    x = dpp_add<0x112, 0xf>(x);   // row_shr:2
    x = dpp_add<0x114, 0xf>(x);   // row_shr:4
    x = dpp_add<0x118, 0xf>(x);   // row_shr:8
    x = dpp_add<0x142, 0xa>(x);   // row_bcast15
    x = dpp_add<0x143, 0xc>(x);   // row_bcast31 -> lane63 = total
    return __int_as_float(__builtin_amdgcn_readlane(__float_as_int(x), 63));
}
__device__ __forceinline__ float wave_max_bcast(float x) {
    x = dpp_max<0x111, 0xf>(x);
    x = dpp_max<0x112, 0xf>(x);
    x = dpp_max<0x114, 0xf>(x);
    x = dpp_max<0x118, 0xf>(x);
    x = dpp_max<0x142, 0xa>(x);
    x = dpp_max<0x143, 0xc>(x);
    return __int_as_float(__builtin_amdgcn_readlane(__float_as_int(x), 63));
}
__device__ __forceinline__ void fma4(float4& a, const float s, const float4& v) {
    a.x += s * v.x; a.y += s * v.y; a.z += s * v.z; a.w += s * v.w;
}

__global__ __launch_bounds__(NT, 4)
void laplace_attn_fused(const float* __restrict__ qg,
                        const float* __restrict__ kg,
                        const float* __restrict__ vg,
                        float* __restrict__ out) {
    // LDS: qs 4KB + dpart 16KB + wt 8KB + po 64KB + red 256B = 92.3 KB.
    __shared__ __align__(16) float  qs[TC][S_];
    __shared__ __align__(16) float  dpart[2][C_][TC];
    __shared__ __align__(16) float  wt[C_][TC];
    __shared__ __align__(16) float4 po[NWA][TC][S_ / 4];
    __shared__ float4 red1[NWH];
    __shared__ float4 red2[NWH];

    const int b    = blockIdx.x;
    const int n    = b & 1;               // XCD x sees only n = x&1
    const int c0   = (b >> 1) * TC;
    const int tid  = threadIdx.x;
    const int w    = tid >> 6;
    const int lane = tid & 63;
    const int d    = tid & (C_ - 1);      // owned d-row
    const int h    = tid >> 9;            // s-half (wave-uniform)

    const float* kn = kg + (size_t)n * C_ * S_;
    const float* vn = vg + (size_t)n * C_ * S_;
    const float* qn = qg + ((size_t)n * C_ + c0) * S_;

    // ---- stage q (4 rows = 256 float4), lane-contiguous ----
    if (tid < TC * (S_ / 4)) {
        const int row = tid >> 6;
        const int col = (tid & 63) << 2;
        *(float4*)&qs[row][col] = *(const float4*)(qn + (size_t)row * S_ + col);
    }
    __syncthreads();

    // ---- logits (split-s): thread owns (d, h); 128 s-elems x 4 c ----
    const float4* kdv = (const float4*)(kn + (size_t)d * S_ + h * SH);
    const int sb = h * SH;
    float dist0 = 0.f, dist1 = 0.f, dist2 = 0.f, dist3 = 0.f;

    #pragma unroll 8
    for (int j = 0; j < SH / 4; ++j) {
        const float4 kf = kdv[j];
        const int s = sb + (j << 2);
        const float4 qa = *(const float4*)&qs[0][s];
        const float4 qb = *(const float4*)&qs[1][s];
        const float4 qc = *(const float4*)&qs[2][s];
        const float4 qd = *(const float4*)&qs[3][s];
        dist0 += (fabsf(kf.x - qa.x) + fabsf(kf.y - qa.y))
               + (fabsf(kf.z - qa.z) + fabsf(kf.w - qa.w));
        dist1 += (fabsf(kf.x - qb.x) + fabsf(kf.y - qb.y))
               + (fabsf(kf.z - qb.z) + fabsf(kf.w - qb.w));
        dist2 += (fabsf(kf.x - qc.x) + fabsf(kf.y - qc.y))
               + (fabsf(kf.z - qc.z) + fabsf(kf.w - qc.w));
        dist3 += (fabsf(kf.x - qd.x) + fabsf(kf.y - qd.y))
               + (fabsf(kf.z - qd.z) + fabsf(kf.w - qd.w));
    }
    *(float4*)&dpart[h][d][0] = make_float4(dist0, dist1, dist2, dist3);
    __syncthreads();

    // ---- softmax on lower 8 waves (barriers stay block-uniform) ----
    const bool act = (tid < C_);          // wave-uniform predicate
    float4 p;
    if (act) {
        const float4 a0 = *(const float4*)&dpart[0][tid][0];
        const float4 a1 = *(const float4*)&dpart[1][tid][0];
        float4 x;
        x.x = -0.5f * (a0.x + a1.x); x.y = -0.5f * (a0.y + a1.y);
        x.z = -0.5f * (a0.z + a1.z); x.w = -0.5f * (a0.w + a1.w);
        p = x;                             // stash logits in p
        float4 mx;
        mx.x = wave_max_bcast(x.x); mx.y = wave_max_bcast(x.y);
        mx.z = wave_max_bcast(x.z); mx.w = wave_max_bcast(x.w);
        if (lane == 0) red1[w] = mx;
    }
    __syncthreads();
    if (act) {
        float4 M = red1[0];
        #pragma unroll
        for (int u = 1; u < NWH; ++u) {
            const float4 r = red1[u];
            M.x = fmaxf(M.x, r.x); M.y = fmaxf(M.y, r.y);
            M.z = fmaxf(M.z, r.z); M.w = fmaxf(M.w, r.w);
        }
        p.x = __expf(p.x - M.x); p.y = __expf(p.y - M.y);
        p.z = __expf(p.z - M.z); p.w = __expf(p.w - M.w);
        float4 sv;
        sv.x = wave_sum_bcast(p.x); sv.y = wave_sum_bcast(p.y);
        sv.z = wave_sum_bcast(p.z); sv.w = wave_sum_bcast(p.w);
        if (lane == 0) red2[w] = sv;
    }
    __syncthreads();
    if (act) {
        float4 L = red2[0];
        #pragma unroll
        for (int u = 1; u < NWH; ++u) {
            const float4 r = red2[u];
            L.x += r.x; L.y += r.y; L.z += r.z; L.w += r.w;
        }
        p.x *= (1.f / L.x); p.y *= (1.f / L.y);
        p.z *= (1.f / L.z); p.w *= (1.f / L.w);
        *(float4*)&wt[tid][0] = p;         // contiguous 16B/thread
    }
    __syncthreads();

    // ---- PV: wave w owns d in [32w, 32w+32); v from global (coalesced) ----
    float4 o0 = make_float4(0.f, 0.f, 0.f, 0.f), o1 = o0, o2 = o0, o3 = o0;
    const int dbase = w * DPW;
    #pragma unroll 8
    for (int dd = 0; dd < DPW; ++dd) {
        const int dr = dbase + dd;
        const float4 vv = *(const float4*)(vn + (size_t)dr * S_ + (lane << 2));
        const float4 pw = *(const float4*)&wt[dr][0];   // uniform broadcast
        fma4(o0, pw.x, vv); fma4(o1, pw.y, vv);
        fma4(o2, pw.z, vv); fma4(o3, pw.w, vv);
    }
    po[w][0][lane] = o0; po[w][1][lane] = o1;
    po[w][2][lane] = o2; po[w][3][lane] = o3;
    __syncthreads();

    // ---- combine 16 wave-partials, write out ----
    if (tid < TC * 64) {
        const int c    = tid >> 6;
        const int quad = tid & 63;
        float4 s = po[0][c][quad];
        #pragma unroll
        for (int u = 1; u < NWA; ++u) {
            const float4 r = po[u][c][quad];
            s.x += r.x; s.y += r.y; s.z += r.z; s.w += r.w;
        }
        *(float4*)(out + ((size_t)n * C_ + c0 + c) * S_ + (quad << 2)) = s;
    }
}

extern "C" void kernel_launch(void* const* d_in, const int* in_sizes, int n_in,
                              void* d_out, int out_size, void* d_ws, size_t ws_size,
                              hipStream_t stream) {
    const float* q = (const float*)d_in[0];
    const float* k = (const float*)d_in[1];
    const float* v = (const float*)d_in[2];
    float* out = (float*)d_out;
    (void)d_ws; (void)ws_size;   // workspace unused

    laplace_attn_fused<<<dim3(N_ * (C_ / TC)), dim3(NT), 0, stream>>>(q, k, v, out);
}